// Round 9
// baseline (244.720 us; speedup 1.0000x reference)
//
#include <hip/hip_runtime.h>
#include <hip/hip_bf16.h>
#include <stdint.h>
#include <math.h>

#define B_DIM 32
#define T_DIM 1024
#define C_DIM 768
#define NTILE 8                 // T_DIM / 128
#define NTRI  36                // NTILE*(NTILE+1)/2
#define NPAIR (NTRI / 2)        // 18 tile-pairs per batch
#define KITER (C_DIM / 64)      // 12 iterations of BK=64

typedef float f32x4 __attribute__((ext_vector_type(4)));

typedef __attribute__((address_space(1))) void gvoid_t;
typedef __attribute__((address_space(3))) void lvoid_t;

// One wave per row: compute 1/||x||_2 and store normalized row as fp8 e4m3.
// Row layout: 768 fp8 bytes = 192 dwords; lane L owns dword L, L+64, L+128
// (elements 4L..4L+3 etc.) -> coalesced dword stores.
__global__ __launch_bounds__(256) void normalize_rows_fp8(const float* __restrict__ x,
                                                          uint32_t* __restrict__ m) {
    const int row  = blockIdx.x * 4 + (threadIdx.x >> 6);
    const int lane = threadIdx.x & 63;
    const float4* xr = (const float4*)(x + (size_t)row * C_DIM);
    float4 v0 = xr[lane];
    float4 v1 = xr[lane + 64];
    float4 v2 = xr[lane + 128];
    float ss = v0.x*v0.x + v0.y*v0.y + v0.z*v0.z + v0.w*v0.w
             + v1.x*v1.x + v1.y*v1.y + v1.z*v1.z + v1.w*v1.w
             + v2.x*v2.x + v2.y*v2.y + v2.z*v2.z + v2.w*v2.w;
    #pragma unroll
    for (int off = 32; off > 0; off >>= 1)
        ss += __shfl_xor(ss, off, 64);
    const float rs = rsqrtf(ss);
    uint32_t* mr = m + (size_t)row * (C_DIM / 4);
    int p;
    p = __builtin_amdgcn_cvt_pk_fp8_f32(v0.x * rs, v0.y * rs, 0, false);
    p = __builtin_amdgcn_cvt_pk_fp8_f32(v0.z * rs, v0.w * rs, p, true);
    mr[lane] = (uint32_t)p;
    p = __builtin_amdgcn_cvt_pk_fp8_f32(v1.x * rs, v1.y * rs, 0, false);
    p = __builtin_amdgcn_cvt_pk_fp8_f32(v1.z * rs, v1.w * rs, p, true);
    mr[lane + 64] = (uint32_t)p;
    p = __builtin_amdgcn_cvt_pk_fp8_f32(v2.x * rs, v2.y * rs, 0, false);
    p = __builtin_amdgcn_cvt_pk_fp8_f32(v2.z * rs, v2.w * rs, p, true);
    mr[lane + 128] = (uint32_t)p;
}

// Batched symmetric NT GEMM on fp8 e4m3: out[b,i,j] = 1 - sum_k M[b,i,k]*M[b,j,k].
// Upper-triangular 128x128 tiles; off-diagonal mirrored via transposed f32x4
// NT stores. Batch-fastest flat grid pins each batch's blocks to one XCD.
//
// THIS ROUND'S ONE CHANGE vs the verified 241.3-us version: each block
// processes TWO tiles of its batch serially (idx and idx+18; 576 blocks).
// Mechanism: previously all 1152 blocks were co-resident and hit the epilogue
// in near-lockstep -> the whole 147 MB output burst was an exposed HBM-write
// tail (~22 us) with no compute left to hide it. Now tile-1's NT stores
// (fire-and-forget) drain underneath tile-2's 12 compute iterations; only
// tile-2's writes remain exposed.
//
// Cross-half WAR safety: half-2's prologue stages only buf[0], whose last
// reads finished before half-1's it=11 barrier; half-2's first in-loop stage
// (buf[1]) sits after its it=0 __syncthreads, which waits for all waves'
// half-1 reads. Per-tile arithmetic and K-order unchanged -> absmax must
// stay bit-identical (0.01403856).
__global__ __launch_bounds__(256) void gemm_nt_sym_fp8(const uint8_t* __restrict__ M,
                                                       float* __restrict__ out) {
    // [buf][ksub][128*32] fp8: 4 KB per sub-block, 16 KB per matrix, 32 KB total.
    __shared__ uint8_t As[2][2][128 * 32];
    __shared__ uint8_t Bs[2][2][128 * 32];

    const int b  = blockIdx.x & 31;   // batch fastest -> batch pinned to XCD (b&7)
    const int tg = blockIdx.x >> 5;   // tile-pair index, 0..17

    const int tid  = threadIdx.x;
    const int wave = tid >> 6;
    const int lane = tid & 63;
    const int quad = lane >> 4;
    const int l16  = lane & 15;
    const int wi = wave >> 1;
    const int wj = wave & 1;

    const uint8_t* Mb = M + (size_t)b * T_DIM * C_DIM;
    float* outb = out + (size_t)b * T_DIM * T_DIM;

    // Staging geometry (tile-independent): each sub-block = 4 chunks of 1 KB;
    // wave w stages chunk w. Chunk rows: w*32..w*32+31 (32 B/row, 2 lanes/row).
    // LDS dest = wave-uniform chunk base + lane*16 (HW rule); content swizzle
    // realized by XOR-ing the global source column.
    const int srow = wave * 32 + (lane >> 1);
    const int scol = ((lane & 1) * 16) ^ ((((srow >> 2) & 1)) << 4);
    const int cbase = wave * 1024;

    // Swizzled ds_read fragment offsets within a 4 KB sub-block:
    // row = w*64 + ii*16 + l16, slot = quad*8, sw = ((l16>>2)&1)<<4.
    const int sw = ((l16 >> 2) & 1) << 4;
    int offA[4], offB[4];
    #pragma unroll
    for (int ii = 0; ii < 4; ++ii) {
        offA[ii] = (wi * 64 + ii * 16 + l16) * 32 + ((quad * 8) ^ sw);
        offB[ii] = (wj * 64 + ii * 16 + l16) * 32 + ((quad * 8) ^ sw);
    }

    for (int half = 0; half < 2; ++half) {
        const int idx = tg + half * NPAIR;   // triangular tile index, 0..35
        int tj = (int)((sqrtf(8.0f * (float)idx + 1.0f) - 1.0f) * 0.5f);
        if (tj * (tj + 1) / 2 > idx) --tj;
        const int ti = idx - tj * (tj + 1) / 2;   // ti <= tj

        const uint8_t* gA = Mb + (size_t)(ti * 128 + srow) * C_DIM + scol;
        const uint8_t* gB = Mb + (size_t)(tj * 128 + srow) * C_DIM + scol;

        f32x4 acc[4][4];
        #pragma unroll
        for (int i = 0; i < 4; ++i)
            #pragma unroll
            for (int j = 0; j < 4; ++j)
                acc[i][j] = (f32x4){0.f, 0.f, 0.f, 0.f};

        // Prologue: stage K-slice 0 (both 32B sub-slices) into buffer 0.
        #pragma unroll
        for (int s = 0; s < 2; ++s) {
            __builtin_amdgcn_global_load_lds((gvoid_t*)(gA + s * 32), (lvoid_t*)&As[0][s][cbase], 16, 0, 0);
            __builtin_amdgcn_global_load_lds((gvoid_t*)(gB + s * 32), (lvoid_t*)&Bs[0][s][cbase], 16, 0, 0);
        }

        for (int it = 0; it < KITER; ++it) {
            const int cur = it & 1;
            // Drains this wave's outstanding stage DMA (vmcnt(0) before
            // barrier) and guarantees all waves finished reading buf[cur^1].
            __syncthreads();
            if (it + 1 < KITER) {
                const int k0 = (it + 1) * 64;   // byte offset along K
                const int nxt = cur ^ 1;
                #pragma unroll
                for (int s = 0; s < 2; ++s) {
                    __builtin_amdgcn_global_load_lds((gvoid_t*)(gA + k0 + s * 32), (lvoid_t*)&As[nxt][s][cbase], 16, 0, 0);
                    __builtin_amdgcn_global_load_lds((gvoid_t*)(gB + k0 + s * 32), (lvoid_t*)&Bs[nxt][s][cbase], 16, 0, 0);
                }
            }

            // Two sub-slices per barrier: {ds_read x8, 16 MFMA} x2.
            #pragma unroll
            for (int s = 0; s < 2; ++s) {
                long af[4], bfr[4];
                #pragma unroll
                for (int ii = 0; ii < 4; ++ii) {
                    af[ii]  = *(const long*)&As[cur][s][offA[ii]];
                    bfr[ii] = *(const long*)&Bs[cur][s][offB[ii]];
                }
                #pragma unroll
                for (int ii = 0; ii < 4; ++ii)
                    #pragma unroll
                    for (int jj = 0; jj < 4; ++jj)
                        acc[ii][jj] = __builtin_amdgcn_mfma_f32_16x16x32_fp8_fp8(af[ii], bfr[jj], acc[ii][jj], 0, 0, 0);
            }
        }

        // Epilogue. C/D layout: col = lane&15, row = quad*4 + reg.
        // NT stores: fire-and-forget; they drain under the next half's compute.
        #pragma unroll
        for (int ii = 0; ii < 4; ++ii) {
            const int rowbase = ti * 128 + wi * 64 + ii * 16 + quad * 4;
            #pragma unroll
            for (int jj = 0; jj < 4; ++jj) {
                const int col = tj * 128 + wj * 64 + jj * 16 + l16;
                #pragma unroll
                for (int r = 0; r < 4; ++r)
                    __builtin_nontemporal_store(1.0f - acc[ii][jj][r],
                                                &outb[(size_t)(rowbase + r) * T_DIM + col]);
            }
        }
        if (ti != tj) {
            // Mirror tile: each lane's 4 acc values share one col and 4
            // consecutive rows -> one aligned f32x4 NT store.
            #pragma unroll
            for (int ii = 0; ii < 4; ++ii) {
                const int rowbase = ti * 128 + wi * 64 + ii * 16 + quad * 4;
                #pragma unroll
                for (int jj = 0; jj < 4; ++jj) {
                    const int col = tj * 128 + wj * 64 + jj * 16 + l16;
                    f32x4 v;
                    v[0] = 1.0f - acc[ii][jj][0];
                    v[1] = 1.0f - acc[ii][jj][1];
                    v[2] = 1.0f - acc[ii][jj][2];
                    v[3] = 1.0f - acc[ii][jj][3];
                    __builtin_nontemporal_store(v, (f32x4*)(outb + (size_t)col * T_DIM + rowbase));
                }
            }
        }
    }
}

extern "C" void kernel_launch(void* const* d_in, const int* in_sizes, int n_in,
                              void* d_out, int out_size, void* d_ws, size_t ws_size,
                              hipStream_t stream) {
    const float* x = (const float*)d_in[0];
    float* out = (float*)d_out;
    uint32_t* metric = (uint32_t*)d_ws;  // 32768 x 768 fp8 = 24 MiB

    normalize_rows_fp8<<<dim3((B_DIM * T_DIM) / 4), dim3(256), 0, stream>>>(x, metric);
    // 576 blocks = 18 tile-pairs x 32 batches, batch-fastest: all of batch b's
    // blocks share XCD (b&7); each block runs tiles idx and idx+18 serially.
    gemm_nt_sym_fp8<<<dim3(NPAIR * B_DIM), dim3(256), 0, stream>>>((const uint8_t*)metric, out);
}

// Round 10
// 242.105 us; speedup vs baseline: 1.0108x; 1.0108x over previous
//
#include <hip/hip_runtime.h>
#include <hip/hip_bf16.h>
#include <stdint.h>
#include <math.h>

#define B_DIM 32
#define T_DIM 1024
#define C_DIM 768
#define NTILE 8                 // T_DIM / 128
#define NTRI  36                // NTILE*(NTILE+1)/2
#define KITER (C_DIM / 64)      // 12 iterations of BK=64

typedef float f32x4 __attribute__((ext_vector_type(4)));

typedef __attribute__((address_space(1))) void gvoid_t;
typedef __attribute__((address_space(3))) void lvoid_t;

// One wave per row: compute 1/||x||_2 and store normalized row as fp8 e4m3.
// Row layout: 768 fp8 bytes = 192 dwords; lane L owns dword L, L+64, L+128
// (elements 4L..4L+3 etc.) -> coalesced dword stores.
__global__ __launch_bounds__(256) void normalize_rows_fp8(const float* __restrict__ x,
                                                          uint32_t* __restrict__ m) {
    const int row  = blockIdx.x * 4 + (threadIdx.x >> 6);
    const int lane = threadIdx.x & 63;
    const float4* xr = (const float4*)(x + (size_t)row * C_DIM);
    float4 v0 = xr[lane];
    float4 v1 = xr[lane + 64];
    float4 v2 = xr[lane + 128];
    float ss = v0.x*v0.x + v0.y*v0.y + v0.z*v0.z + v0.w*v0.w
             + v1.x*v1.x + v1.y*v1.y + v1.z*v1.z + v1.w*v1.w
             + v2.x*v2.x + v2.y*v2.y + v2.z*v2.z + v2.w*v2.w;
    #pragma unroll
    for (int off = 32; off > 0; off >>= 1)
        ss += __shfl_xor(ss, off, 64);
    const float rs = rsqrtf(ss);
    uint32_t* mr = m + (size_t)row * (C_DIM / 4);
    int p;
    p = __builtin_amdgcn_cvt_pk_fp8_f32(v0.x * rs, v0.y * rs, 0, false);
    p = __builtin_amdgcn_cvt_pk_fp8_f32(v0.z * rs, v0.w * rs, p, true);
    mr[lane] = (uint32_t)p;
    p = __builtin_amdgcn_cvt_pk_fp8_f32(v1.x * rs, v1.y * rs, 0, false);
    p = __builtin_amdgcn_cvt_pk_fp8_f32(v1.z * rs, v1.w * rs, p, true);
    mr[lane + 64] = (uint32_t)p;
    p = __builtin_amdgcn_cvt_pk_fp8_f32(v2.x * rs, v2.y * rs, 0, false);
    p = __builtin_amdgcn_cvt_pk_fp8_f32(v2.z * rs, v2.w * rs, p, true);
    mr[lane + 128] = (uint32_t)p;
}

// Batched symmetric NT GEMM on fp8 e4m3: out[b,i,j] = 1 - sum_k M[b,i,k]*M[b,j,k].
// Upper-triangular 128x128 tiles only; off-diagonal mirrored via transposed
// f32x4 stores. Batch-fastest flat grid pins each batch's 36 blocks to one XCD.
//
// Verified-best configuration (R8, 241.3 us, absmax 0.01403856):
//  - BK=64 K-loop (12 iters; barrier count halved vs BK=32 -> -6.2 us, R4)
//  - nontemporal epilogue stores (output never re-read; -2.7 us, R8)
//  - 16B-granule LDS half-swizzle via pre-swizzled global source column
//  - single-barrier LDS double-buffer: stage(next) issued right after the
//    barrier, drained by the NEXT barrier's vmcnt(0), overlapping compute.
// Structural alternatives all measured and rejected: counted-vmcnt ring (R1,
// null), fused ws-free (R3, -45), barrier-free per-wave tiles (R7, -14),
// 2-tile write-tail pipelining (R9, null).
__global__ __launch_bounds__(256) void gemm_nt_sym_fp8(const uint8_t* __restrict__ M,
                                                       float* __restrict__ out) {
    // [buf][ksub][128*32] fp8: 4 KB per sub-block, 16 KB per matrix, 32 KB total.
    __shared__ uint8_t As[2][2][128 * 32];
    __shared__ uint8_t Bs[2][2][128 * 32];

    const int b   = blockIdx.x & 31;   // batch fastest -> batch pinned to XCD (b&7)
    const int idx = blockIdx.x >> 5;   // triangular tile index, 0..35
    int tj = (int)((sqrtf(8.0f * (float)idx + 1.0f) - 1.0f) * 0.5f);
    if (tj * (tj + 1) / 2 > idx) --tj;
    const int ti = idx - tj * (tj + 1) / 2;   // ti <= tj

    const int tid  = threadIdx.x;
    const int wave = tid >> 6;
    const int lane = tid & 63;
    const int quad = lane >> 4;
    const int l16  = lane & 15;
    const int wi = wave >> 1;
    const int wj = wave & 1;

    const uint8_t* Mb = M + (size_t)b * T_DIM * C_DIM;

    // Staging: each sub-block = 4 chunks of 1 KB; wave w stages chunk w.
    // Chunk rows: w*32 .. w*32+31 (32 B/row in the sub-block, 2 lanes per row).
    // LDS dest = wave-uniform chunk base + lane*16 (HW rule); the content
    // permutation is realized by XOR-ing the global source column.
    const int srow = wave * 32 + (lane >> 1);
    const int scol = ((lane & 1) * 16) ^ ((((srow >> 2) & 1)) << 4);

    const uint8_t* gA = Mb + (size_t)(ti * 128 + srow) * C_DIM + scol;
    const uint8_t* gB = Mb + (size_t)(tj * 128 + srow) * C_DIM + scol;
    const int cbase = wave * 1024;

    // Swizzled ds_read fragment offsets within a 4 KB sub-block:
    // row = w*64 + ii*16 + l16, slot = quad*8, sw = ((l16>>2)&1)<<4.
    const int sw = ((l16 >> 2) & 1) << 4;
    int offA[4], offB[4];
    #pragma unroll
    for (int ii = 0; ii < 4; ++ii) {
        offA[ii] = (wi * 64 + ii * 16 + l16) * 32 + ((quad * 8) ^ sw);
        offB[ii] = (wj * 64 + ii * 16 + l16) * 32 + ((quad * 8) ^ sw);
    }

    f32x4 acc[4][4];
    #pragma unroll
    for (int i = 0; i < 4; ++i)
        #pragma unroll
        for (int j = 0; j < 4; ++j)
            acc[i][j] = (f32x4){0.f, 0.f, 0.f, 0.f};

    // Prologue: stage K-slice 0 (both 32B sub-slices) into buffer 0.
    #pragma unroll
    for (int s = 0; s < 2; ++s) {
        __builtin_amdgcn_global_load_lds((gvoid_t*)(gA + s * 32), (lvoid_t*)&As[0][s][cbase], 16, 0, 0);
        __builtin_amdgcn_global_load_lds((gvoid_t*)(gB + s * 32), (lvoid_t*)&Bs[0][s][cbase], 16, 0, 0);
    }

    for (int it = 0; it < KITER; ++it) {
        const int cur = it & 1;
        // Drains this wave's outstanding stage DMA (vmcnt(0) before barrier) and
        // guarantees all waves finished reading buf[cur^1] from iter it-1.
        __syncthreads();
        if (it + 1 < KITER) {
            const int k0 = (it + 1) * 64;   // byte offset along K
            const int nxt = cur ^ 1;
            #pragma unroll
            for (int s = 0; s < 2; ++s) {
                __builtin_amdgcn_global_load_lds((gvoid_t*)(gA + k0 + s * 32), (lvoid_t*)&As[nxt][s][cbase], 16, 0, 0);
                __builtin_amdgcn_global_load_lds((gvoid_t*)(gB + k0 + s * 32), (lvoid_t*)&Bs[nxt][s][cbase], 16, 0, 0);
            }
        }

        // Two sub-slices per barrier: {ds_read x8, 16 MFMA} x2. K-summation
        // order per output element is identical to the BK=32 version.
        #pragma unroll
        for (int s = 0; s < 2; ++s) {
            long af[4], bfr[4];
            #pragma unroll
            for (int ii = 0; ii < 4; ++ii) {
                af[ii]  = *(const long*)&As[cur][s][offA[ii]];
                bfr[ii] = *(const long*)&Bs[cur][s][offB[ii]];
            }
            #pragma unroll
            for (int ii = 0; ii < 4; ++ii)
                #pragma unroll
                for (int jj = 0; jj < 4; ++jj)
                    acc[ii][jj] = __builtin_amdgcn_mfma_f32_16x16x32_fp8_fp8(af[ii], bfr[jj], acc[ii][jj], 0, 0, 0);
        }
    }

    // Epilogue. C/D layout: col = lane&15, row = quad*4 + reg. out = 1 - acc.
    // All stores NONTEMPORAL (output is never re-read; keep it out of L2).
    float* outb = out + (size_t)b * T_DIM * T_DIM;
    #pragma unroll
    for (int ii = 0; ii < 4; ++ii) {
        const int rowbase = ti * 128 + wi * 64 + ii * 16 + quad * 4;
        #pragma unroll
        for (int jj = 0; jj < 4; ++jj) {
            const int col = tj * 128 + wj * 64 + jj * 16 + l16;
            #pragma unroll
            for (int r = 0; r < 4; ++r)
                __builtin_nontemporal_store(1.0f - acc[ii][jj][r],
                                            &outb[(size_t)(rowbase + r) * T_DIM + col]);
        }
    }
    if (ti != tj) {
        // Mirror tile: each lane's 4 acc values share one col and 4 consecutive
        // rows -> one aligned f32x4 store; 4 quads of same l16 cover a 64B line.
        #pragma unroll
        for (int ii = 0; ii < 4; ++ii) {
            const int rowbase = ti * 128 + wi * 64 + ii * 16 + quad * 4;
            #pragma unroll
            for (int jj = 0; jj < 4; ++jj) {
                const int col = tj * 128 + wj * 64 + jj * 16 + l16;
                f32x4 v;
                v[0] = 1.0f - acc[ii][jj][0];
                v[1] = 1.0f - acc[ii][jj][1];
                v[2] = 1.0f - acc[ii][jj][2];
                v[3] = 1.0f - acc[ii][jj][3];
                __builtin_nontemporal_store(v, (f32x4*)(outb + (size_t)col * T_DIM + rowbase));
            }
        }
    }
}

extern "C" void kernel_launch(void* const* d_in, const int* in_sizes, int n_in,
                              void* d_out, int out_size, void* d_ws, size_t ws_size,
                              hipStream_t stream) {
    const float* x = (const float*)d_in[0];
    float* out = (float*)d_out;
    uint32_t* metric = (uint32_t*)d_ws;  // 32768 x 768 fp8 = 24 MiB

    normalize_rows_fp8<<<dim3((B_DIM * T_DIM) / 4), dim3(256), 0, stream>>>(x, metric);
    // 1152 blocks, batch-fastest: all 36 tiles of batch b share XCD (b&7).
    gemm_nt_sym_fp8<<<dim3(NTRI * B_DIM), dim3(256), 0, stream>>>((const uint8_t*)metric, out);
}